// Round 1
// baseline (537.374 us; speedup 1.0000x reference)
//
#include <hip/hip_runtime.h>
#include <hip/hip_bf16.h>

// Problem constants (LinearRNN): B=16, T=4096, D_IN=256, HID=512, D_OUT=256
#define BATCH 16
#define SEQT  4096
#define DIN   256
#define HID   512
#define DOUT  256
#define M_TOT (BATCH * SEQT)      // 65536
#define NCHUNK 64                 // chunks along T
#define CLEN   64                 // chunk length (NCHUNK*CLEN == SEQT)

#define BM 128
#define BN 128
#define BK 16

// ---------------------------------------------------------------------------
// GEMM (NT): C[M,N] = A[M,K] * B[N,K]^T, fp32, all dims divisible by tiles.
// ---------------------------------------------------------------------------
__global__ __launch_bounds__(256) void gemm_nt(const float* __restrict__ A,
                                               const float* __restrict__ Bm,
                                               float* __restrict__ C,
                                               int M, int N, int K) {
    __shared__ float As[BK][BM];
    __shared__ float Bs[BK][BN];

    const int tid = threadIdx.x;
    const int tx = tid & 15;   // n-direction, 0..15
    const int ty = tid >> 4;   // m-direction, 0..15

    const size_t mBase = (size_t)blockIdx.x * BM;
    const size_t nBase = (size_t)blockIdx.y * BN;
    const float* Ab = A + mBase * (size_t)K;
    const float* Bb = Bm + nBase * (size_t)K;

    float acc[8][8];
    for (int i = 0; i < 8; ++i)
        for (int j = 0; j < 8; ++j) acc[i][j] = 0.f;

    const int lr = tid >> 2;         // 0..63
    const int lc = (tid & 3) * 4;    // 0,4,8,12

    for (int k0 = 0; k0 < K; k0 += BK) {
        #pragma unroll
        for (int r = 0; r < 2; ++r) {
            const int row = lr + r * 64;
            const float4 av = *(const float4*)(Ab + (size_t)row * K + k0 + lc);
            const float4 bv = *(const float4*)(Bb + (size_t)row * K + k0 + lc);
            As[lc + 0][row] = av.x; As[lc + 1][row] = av.y;
            As[lc + 2][row] = av.z; As[lc + 3][row] = av.w;
            Bs[lc + 0][row] = bv.x; Bs[lc + 1][row] = bv.y;
            Bs[lc + 2][row] = bv.z; Bs[lc + 3][row] = bv.w;
        }
        __syncthreads();
        #pragma unroll
        for (int k = 0; k < BK; ++k) {
            float a[8], b[8];
            *(float4*)&a[0] = *(const float4*)&As[k][ty * 8];
            *(float4*)&a[4] = *(const float4*)&As[k][ty * 8 + 4];
            *(float4*)&b[0] = *(const float4*)&Bs[k][tx * 8];
            *(float4*)&b[4] = *(const float4*)&Bs[k][tx * 8 + 4];
            #pragma unroll
            for (int i = 0; i < 8; ++i)
                #pragma unroll
                for (int j = 0; j < 8; ++j)
                    acc[i][j] = fmaf(a[i], b[j], acc[i][j]);
        }
        __syncthreads();
    }

    #pragma unroll
    for (int i = 0; i < 8; ++i) {
        const size_t crow = mBase + ty * 8 + i;
        float4 v0, v1;
        v0.x = acc[i][0]; v0.y = acc[i][1]; v0.z = acc[i][2]; v0.w = acc[i][3];
        v1.x = acc[i][4]; v1.y = acc[i][5]; v1.z = acc[i][6]; v1.w = acc[i][7];
        *(float4*)(C + crow * N + nBase + tx * 8)     = v0;
        *(float4*)(C + crow * N + nBase + tx * 8 + 4) = v1;
    }
}

// ---------------------------------------------------------------------------
// prep: wdiag[h] = W_h[h,h]; wpow[tl][h] = w^(tl+1), tl in [0,64)
// (wpow[63][h] == w^64 is the per-chunk carry factor)
// ---------------------------------------------------------------------------
__global__ void prep_kernel(const float* __restrict__ Wh,
                            float* __restrict__ wdiag,
                            float* __restrict__ wpow) {
    const int h = threadIdx.x;  // 512 threads
    const float w = Wh[(size_t)h * HID + h];
    wdiag[h] = w;
    float p = 1.f;
    for (int tl = 0; tl < CLEN; ++tl) {
        p *= w;
        wpow[(size_t)tl * HID + h] = p;
    }
}

// ---------------------------------------------------------------------------
// local scan within each chunk (in place on xp), emit chunk-final local state
// thread = (c, b, h); 64*16*512 = 524288 threads
// ---------------------------------------------------------------------------
__global__ __launch_bounds__(256) void scan_local(float* __restrict__ xp,
                                                  const float* __restrict__ wdiag,
                                                  float* __restrict__ L) {
    const size_t idx = (size_t)blockIdx.x * 256 + threadIdx.x;
    const int h = (int)(idx & (HID - 1));
    const size_t bc = idx >> 9;            // b*? : bc = c*16 + ... define below
    const int b = (int)(bc & (BATCH - 1)); // bc = c*BATCH + b
    const int c = (int)(bc >> 4);
    if (c >= NCHUNK) return;

    const float w = wdiag[h];
    size_t base = (((size_t)b * SEQT + (size_t)c * CLEN) * HID) + h;
    float local = 0.f;
    for (int tl = 0; tl < CLEN; ++tl) {
        const float v = xp[base];
        local = fmaf(w, local, v);
        xp[base] = local;
        base += HID;
    }
    L[((size_t)c * BATCH + b) * HID + h] = local;
}

// ---------------------------------------------------------------------------
// sequential carry across chunks. thread = (b, h); 8192 threads
// carry[c][b][h] = true state entering chunk c
// ---------------------------------------------------------------------------
__global__ __launch_bounds__(256) void scan_carry(const float* __restrict__ L,
                                                  const float* __restrict__ w64,
                                                  float* __restrict__ carry) {
    const size_t idx = (size_t)blockIdx.x * 256 + threadIdx.x;
    const int h = (int)(idx & (HID - 1));
    const int b = (int)(idx >> 9);
    if (b >= BATCH) return;

    const float wf = w64[h];
    float H = 0.f;
    for (int c = 0; c < NCHUNK; ++c) {
        const size_t o = ((size_t)c * BATCH + b) * HID + h;
        carry[o] = H;
        H = fmaf(wf, H, L[o]);
    }
}

// ---------------------------------------------------------------------------
// fix: hs_t = local_t + w^(tl+1) * carry[c]   (in place on xp, float4)
// ---------------------------------------------------------------------------
__global__ __launch_bounds__(256) void scan_fix(float* __restrict__ xp,
                                                const float* __restrict__ wpow,
                                                const float* __restrict__ carry) {
    const size_t total4 = (size_t)M_TOT * HID / 4;  // 8388608
    for (size_t e4 = (size_t)blockIdx.x * 256 + threadIdx.x; e4 < total4;
         e4 += (size_t)gridDim.x * 256) {
        const size_t e = e4 * 4;
        const int h = (int)(e & (HID - 1));
        const size_t m = e >> 9;
        const int t = (int)(m & (SEQT - 1));
        const int b = (int)(m >> 12);
        const int c = t >> 6;
        const int tl = t & (CLEN - 1);

        float4 loc = *(float4*)(xp + e);
        const float4 wp = *(const float4*)(wpow + (size_t)tl * HID + h);
        const float4 cr = *(const float4*)(carry + ((size_t)c * BATCH + b) * HID + h);
        loc.x = fmaf(wp.x, cr.x, loc.x);
        loc.y = fmaf(wp.y, cr.y, loc.y);
        loc.z = fmaf(wp.z, cr.z, loc.z);
        loc.w = fmaf(wp.w, cr.w, loc.w);
        *(float4*)(xp + e) = loc;
    }
}

// ---------------------------------------------------------------------------
extern "C" void kernel_launch(void* const* d_in, const int* in_sizes, int n_in,
                              void* d_out, int out_size, void* d_ws, size_t ws_size,
                              hipStream_t stream) {
    const float* x     = (const float*)d_in[0];   // [16,4096,256]
    const float* W_in  = (const float*)d_in[1];   // [512,256]
    const float* W_h   = (const float*)d_in[2];   // [512,512] (diagonal)
    const float* W_out = (const float*)d_in[3];   // [256,512]
    float* out = (float*)d_out;                    // [16,4096,256]

    // workspace layout (bytes)
    char* ws = (char*)d_ws;
    float* xp    = (float*)(ws);                                   // 134217728 B
    float* L     = (float*)(ws + 134217728);                       // 2097152 B
    float* carry = (float*)(ws + 134217728 + 2097152);             // 2097152 B
    float* wpow  = (float*)(ws + 134217728 + 2 * 2097152);         // 131072 B
    float* wdiag = (float*)(ws + 134217728 + 2 * 2097152 + 131072);// 2048 B
    float* w64   = wpow + (size_t)(CLEN - 1) * HID;                // == w^64 row

    // 1) xp = x @ W_in^T   [65536,512]
    gemm_nt<<<dim3(M_TOT / BM, HID / BN), 256, 0, stream>>>(x, W_in, xp,
                                                            M_TOT, HID, DIN);
    // 2) diag + power table
    prep_kernel<<<1, HID, 0, stream>>>(W_h, wdiag, wpow);
    // 3) local scan per chunk (in place)
    scan_local<<<(NCHUNK * BATCH * HID) / 256, 256, 0, stream>>>(xp, wdiag, L);
    // 4) carry across chunks
    scan_carry<<<(BATCH * HID) / 256, 256, 0, stream>>>(L, w64, carry);
    // 5) apply carry correction (in place)
    scan_fix<<<2048, 256, 0, stream>>>(xp, wpow, carry);
    // 6) out = hs @ W_out^T   [65536,256]
    gemm_nt<<<dim3(M_TOT / BM, DOUT / BN), 256, 0, stream>>>(xp, W_out, out,
                                                             M_TOT, DOUT, HID);
}

// Round 2
// 281.127 us; speedup vs baseline: 1.9115x; 1.9115x over previous
//
#include <hip/hip_runtime.h>
#include <hip/hip_bf16.h>

// Problem constants (LinearRNN): B=16, T=4096, D_IN=256, HID=512, D_OUT=256
#define BATCH 16
#define SEQT  4096
#define DIN   256
#define HID   512
#define DOUT  256
#define M_TOT (BATCH * SEQT)      // 65536
#define NCHUNK 64                 // chunks along T
#define CLEN   64                 // chunk length

#define LDK 72                    // LDS row stride in shorts (64 + 8 pad)

typedef short  bf16x8 __attribute__((ext_vector_type(8)));
typedef float  f32x4  __attribute__((ext_vector_type(4)));
typedef unsigned short u16x4 __attribute__((ext_vector_type(4)));

// fp32 -> bf16 round-to-nearest-even
__device__ inline unsigned short f2bf(float f) {
    unsigned u = __float_as_uint(f);
    u += 0x7FFF + ((u >> 16) & 1);
    return (unsigned short)(u >> 16);
}

// split fp32x4 into hi/lo bf16x4 (a = hi + lo, ~16-bit combined mantissa)
__device__ inline void split4(const float4 v, u16x4* hi, u16x4* lo) {
    float f[4] = {v.x, v.y, v.z, v.w};
    u16x4 h, l;
#pragma unroll
    for (int i = 0; i < 4; ++i) {
        const unsigned short hb = f2bf(f[i]);
        const float hf = __uint_as_float((unsigned)hb << 16);
        h[i] = (unsigned short)hb;
        l[i] = f2bf(f[i] - hf);
    }
    *hi = h;
    *lo = l;
}

// ---------------------------------------------------------------------------
// Split-bf16 MFMA GEMM (NT): C[M,N] = A[M,K] * W[N,K]^T, fp32 in/out.
// BM=BN=128, BK=64, 256 threads = 4 waves, each wave owns a 64x64 quadrant
// as 4x4 fragments of 16x16 (mfma_f32_16x16x32_bf16).
// FIX: A is xp-local state; apply hs = local + w^(tl+1)*carry[c,b] on load.
// ---------------------------------------------------------------------------
template<int K, int N, bool FIX>
__global__ __launch_bounds__(256, 2) void gemm_mfma(
        const float* __restrict__ A, const float* __restrict__ W,
        float* __restrict__ C,
        const float* __restrict__ wpow, const float* __restrict__ carry) {
    __shared__ __align__(16) unsigned short Ahi[128][LDK];
    __shared__ __align__(16) unsigned short Alo[128][LDK];
    __shared__ __align__(16) unsigned short Bhi[128][LDK];
    __shared__ __align__(16) unsigned short Blo[128][LDK];

    const int tid = threadIdx.x;
    const size_t mBase = (size_t)blockIdx.x * 128;
    const int nBase = blockIdx.y * 128;

    // staging assignment: 16 threads cover one row's 64 fp32 (coalesced 256B)
    const int trow = tid >> 4;        // 0..15 (+16 per iter)
    const int tc4  = (tid & 15) * 4;  // fp32 col within the 64-wide chunk

    // wave/fragment assignment
    const int w    = tid >> 6;
    const int lane = tid & 63;
    const int wr = w >> 1, wc = w & 1; // wave quadrant (2x2 of 64x64)
    const int fr = lane & 15;          // row/col within 16x16 fragment
    const int kg = lane >> 4;          // k-group (8 bf16 each)

    f32x4 acc[4][4];
#pragma unroll
    for (int i = 0; i < 4; ++i)
#pragma unroll
        for (int j = 0; j < 4; ++j)
            acc[i][j] = (f32x4){0.f, 0.f, 0.f, 0.f};

    for (int k0 = 0; k0 < K; k0 += 64) {
#pragma unroll
        for (int r = 0; r < 8; ++r) {
            const int row = trow + r * 16;
            const size_t gm = mBase + row;
            float4 av = *(const float4*)(A + gm * K + k0 + tc4);
            if (FIX) {
                const int t  = (int)(gm & (SEQT - 1));
                const int b  = (int)(gm >> 12);
                const int c  = t >> 6;
                const int tl = t & (CLEN - 1);
                const float4 wp = *(const float4*)(wpow + (size_t)tl * HID + k0 + tc4);
                const float4 cr = *(const float4*)(carry + ((size_t)(c * BATCH + b)) * HID + k0 + tc4);
                av.x = fmaf(wp.x, cr.x, av.x);
                av.y = fmaf(wp.y, cr.y, av.y);
                av.z = fmaf(wp.z, cr.z, av.z);
                av.w = fmaf(wp.w, cr.w, av.w);
            }
            split4(av, (u16x4*)&Ahi[row][tc4], (u16x4*)&Alo[row][tc4]);

            const float4 bv = *(const float4*)(W + (size_t)(nBase + row) * K + k0 + tc4);
            split4(bv, (u16x4*)&Bhi[row][tc4], (u16x4*)&Blo[row][tc4]);
        }
        __syncthreads();

#pragma unroll
        for (int ks = 0; ks < 2; ++ks) {
            const int kk = ks * 32 + kg * 8;
            bf16x8 ah[4], al[4], bh[4], bl[4];
#pragma unroll
            for (int f = 0; f < 4; ++f) {
                ah[f] = *(const bf16x8*)&Ahi[wr * 64 + f * 16 + fr][kk];
                al[f] = *(const bf16x8*)&Alo[wr * 64 + f * 16 + fr][kk];
                bh[f] = *(const bf16x8*)&Bhi[wc * 64 + f * 16 + fr][kk];
                bl[f] = *(const bf16x8*)&Blo[wc * 64 + f * 16 + fr][kk];
            }
#pragma unroll
            for (int i = 0; i < 4; ++i)
#pragma unroll
                for (int j = 0; j < 4; ++j) {
                    acc[i][j] = __builtin_amdgcn_mfma_f32_16x16x32_bf16(ah[i], bh[j], acc[i][j], 0, 0, 0);
                    acc[i][j] = __builtin_amdgcn_mfma_f32_16x16x32_bf16(ah[i], bl[j], acc[i][j], 0, 0, 0);
                    acc[i][j] = __builtin_amdgcn_mfma_f32_16x16x32_bf16(al[i], bh[j], acc[i][j], 0, 0, 0);
                }
        }
        __syncthreads();
    }

    // epilogue: C/D layout col = lane&15, row = (lane>>4)*4 + reg (m89/m91)
#pragma unroll
    for (int i = 0; i < 4; ++i) {
        const size_t row0 = mBase + wr * 64 + i * 16 + kg * 4;
#pragma unroll
        for (int j = 0; j < 4; ++j) {
            const int col = nBase + wc * 64 + j * 16 + fr;
#pragma unroll
            for (int rg = 0; rg < 4; ++rg)
                C[(row0 + rg) * N + col] = acc[i][j][rg];
        }
    }
}

// ---------------------------------------------------------------------------
// prep: wdiag[h] = W_h[h,h]; wpow[tl][h] = w^(tl+1), tl in [0,64)
// (wpow[63][h] == w^64 is the per-chunk carry factor)
// ---------------------------------------------------------------------------
__global__ void prep_kernel(const float* __restrict__ Wh,
                            float* __restrict__ wdiag,
                            float* __restrict__ wpow) {
    const int h = threadIdx.x;  // 512 threads
    const float w = Wh[(size_t)h * HID + h];
    wdiag[h] = w;
    float p = 1.f;
    for (int tl = 0; tl < CLEN; ++tl) {
        p *= w;
        wpow[(size_t)tl * HID + h] = p;
    }
}

// ---------------------------------------------------------------------------
// local scan within each chunk (in place on xp), emit chunk-final local state
// thread = (c, b, h); 64*16*512 = 524288 threads
// ---------------------------------------------------------------------------
__global__ __launch_bounds__(256) void scan_local(float* __restrict__ xp,
                                                  const float* __restrict__ wdiag,
                                                  float* __restrict__ L) {
    const size_t idx = (size_t)blockIdx.x * 256 + threadIdx.x;
    const int h = (int)(idx & (HID - 1));
    const size_t bc = idx >> 9;
    const int b = (int)(bc & (BATCH - 1)); // bc = c*BATCH + b
    const int c = (int)(bc >> 4);
    if (c >= NCHUNK) return;

    const float w = wdiag[h];
    size_t base = (((size_t)b * SEQT + (size_t)c * CLEN) * HID) + h;
    float local = 0.f;
    for (int tl = 0; tl < CLEN; ++tl) {
        const float v = xp[base];
        local = fmaf(w, local, v);
        xp[base] = local;
        base += HID;
    }
    L[((size_t)c * BATCH + b) * HID + h] = local;
}

// ---------------------------------------------------------------------------
// sequential carry across chunks. thread = (b, h); 8192 threads
// carry[c][b][h] = true state entering chunk c
// ---------------------------------------------------------------------------
__global__ __launch_bounds__(256) void scan_carry(const float* __restrict__ L,
                                                  const float* __restrict__ w64,
                                                  float* __restrict__ carry) {
    const size_t idx = (size_t)blockIdx.x * 256 + threadIdx.x;
    const int h = (int)(idx & (HID - 1));
    const int b = (int)(idx >> 9);
    if (b >= BATCH) return;

    const float wf = w64[h];
    float H = 0.f;
    for (int c = 0; c < NCHUNK; ++c) {
        const size_t o = ((size_t)c * BATCH + b) * HID + h;
        carry[o] = H;
        H = fmaf(wf, H, L[o]);
    }
}

// ---------------------------------------------------------------------------
extern "C" void kernel_launch(void* const* d_in, const int* in_sizes, int n_in,
                              void* d_out, int out_size, void* d_ws, size_t ws_size,
                              hipStream_t stream) {
    const float* x     = (const float*)d_in[0];   // [16,4096,256]
    const float* W_in  = (const float*)d_in[1];   // [512,256]
    const float* W_h   = (const float*)d_in[2];   // [512,512] (diagonal)
    const float* W_out = (const float*)d_in[3];   // [256,512]
    float* out = (float*)d_out;                    // [16,4096,256]

    // workspace layout (bytes)
    char* ws = (char*)d_ws;
    float* xp    = (float*)(ws);                                    // 134217728 B
    float* L     = (float*)(ws + 134217728);                        // 2097152 B
    float* carry = (float*)(ws + 134217728 + 2097152);              // 2097152 B
    float* wpow  = (float*)(ws + 134217728 + 2 * 2097152);          // 131072 B
    float* wdiag = (float*)(ws + 134217728 + 2 * 2097152 + 131072); // 2048 B
    float* w64   = wpow + (size_t)(CLEN - 1) * HID;                 // w^64 row

    // 1) xp = x @ W_in^T   [65536,512]  (split-bf16 MFMA)
    gemm_mfma<DIN, HID, false><<<dim3(M_TOT / 128, HID / 128), 256, 0, stream>>>(
        x, W_in, xp, nullptr, nullptr);
    // 2) diag + power table
    prep_kernel<<<1, HID, 0, stream>>>(W_h, wdiag, wpow);
    // 3) local scan per chunk (in place on xp)
    scan_local<<<(NCHUNK * BATCH * HID) / 256, 256, 0, stream>>>(xp, wdiag, L);
    // 4) carry across chunks
    scan_carry<<<(BATCH * HID) / 256, 256, 0, stream>>>(L, w64, carry);
    // 5) out = (local + wpow*carry) @ W_out^T, fix fused into A-staging
    gemm_mfma<HID, DOUT, true><<<dim3(M_TOT / 128, DOUT / 128), 256, 0, stream>>>(
        xp, W_out, out, wpow, carry);
}

// Round 3
// 199.746 us; speedup vs baseline: 2.6903x; 1.4074x over previous
//
#include <hip/hip_runtime.h>
#include <hip/hip_bf16.h>
#include <stdint.h>

// Problem constants (LinearRNN): B=16, T=4096, D_IN=256, HID=512, D_OUT=256
#define BATCH 16
#define SEQT  4096
#define DIN   256
#define HID   512
#define DOUT  256
#define M_TOT 65536
#define CLEN  128                 // chunk length (== GEMM1 block M-tile)
#define NCHUNK 32                 // SEQT / CLEN

typedef short bf16x8 __attribute__((ext_vector_type(8)));
typedef float f32x4  __attribute__((ext_vector_type(4)));
typedef unsigned short u16;
typedef unsigned short u16x4 __attribute__((ext_vector_type(4)));
typedef unsigned int uint32;

// async global->LDS, 16B per lane; LDS dest is wave-uniform base + lane*16
__device__ __forceinline__ void ld_lds16(const void* g, void* l) {
    __builtin_amdgcn_global_load_lds(
        (const __attribute__((address_space(1))) void*)g,
        (__attribute__((address_space(3))) void*)l, 16, 0, 0);
}

__device__ __forceinline__ u16 f2bf_rne(float f) {
    uint32 v = __float_as_uint(f);
    v += 0x7FFFu + ((v >> 16) & 1u);
    return (u16)(v >> 16);
}

// trunc-hi / rne-lo split: f ~= hi + lo, ~17-bit combined mantissa
__device__ __forceinline__ void splitf(float f, u16& hi, u16& lo) {
    const uint32 u = __float_as_uint(f);
    hi = (u16)(u >> 16);
    lo = f2bf_rne(f - __uint_as_float(u & 0xFFFF0000u));
}

__device__ __forceinline__ float bf2f(u16 s) {
    return __uint_as_float((uint32)s << 16);
}

// ---------------------------------------------------------------------------
// prep: block 0 -> wdiag + wpow (w^(tl+1), tl<128); blocks 1..128 -> W_in
// split; blocks 129..256 -> W_out split.
// ---------------------------------------------------------------------------
__global__ __launch_bounds__(256) void prep(
        const float* __restrict__ Wh, const float* __restrict__ Win,
        const float* __restrict__ Wout, float* __restrict__ wdiag,
        float* __restrict__ wpow, u16* __restrict__ Winhi,
        u16* __restrict__ Winlo, u16* __restrict__ Wouthi,
        u16* __restrict__ Woutlo) {
    const int bid = blockIdx.x, tid = threadIdx.x;
    if (bid == 0) {
        for (int h = tid; h < HID; h += 256) {
            const float wv = Wh[(size_t)h * HID + h];
            wdiag[h] = wv;
            float p = 1.f;
            for (int t = 0; t < CLEN; ++t) { p *= wv; wpow[t * HID + h] = p; }
        }
    } else if (bid <= 128) {
        const int f4 = (bid - 1) * 256 + tid;   // < 32768
        const f32x4 v = *(const f32x4*)(Win + (size_t)f4 * 4);
        u16x4 hv, lv;
#pragma unroll
        for (int k = 0; k < 4; ++k) { u16 a, b; splitf(v[k], a, b); hv[k] = a; lv[k] = b; }
        *(u16x4*)(Winhi + (size_t)f4 * 4) = hv;
        *(u16x4*)(Winlo + (size_t)f4 * 4) = lv;
    } else {
        const int f4 = (bid - 129) * 256 + tid;
        const f32x4 v = *(const f32x4*)(Wout + (size_t)f4 * 4);
        u16x4 hv, lv;
#pragma unroll
        for (int k = 0; k < 4; ++k) { u16 a, b; splitf(v[k], a, b); hv[k] = a; lv[k] = b; }
        *(u16x4*)(Wouthi + (size_t)f4 * 4) = hv;
        *(u16x4*)(Woutlo + (size_t)f4 * 4) = lv;
    }
}

// ---------------------------------------------------------------------------
// GEMM1 + fused local scan: xp = x @ W_in^T per 128x128 tile, then scan the
// tile along t (block rows == one full chunk), write local state as split
// bf16 + chunk-final L. A staged fp32 via global_load_lds (swizzled), split
// per-fragment in-register; B pre-split bf16.
// ---------------------------------------------------------------------------
__global__ __launch_bounds__(256, 2) void gemm1_scan(
        const float* __restrict__ X, const u16* __restrict__ Whi,
        const u16* __restrict__ Wlo, u16* __restrict__ localhi,
        u16* __restrict__ locallo, float* __restrict__ L,
        const float* __restrict__ wdiag) {
    __shared__ __align__(16) char smem[67584];
    float* As = (float*)smem;               // [128][64] f32 (32 chunks of 1KB), swizzled
    u16*   Bh = (u16*)(smem + 32768);       // [128][64] bf16, swizzled
    u16*   Bl = (u16*)(smem + 49152);
    float* st = (float*)smem;               // scan tile [128][132] f32 (aliased)

    const int tid  = threadIdx.x;
    const int w    = tid >> 6;
    const int lane = tid & 63;
    const int mBase = blockIdx.x * 128;
    const int nBase = blockIdx.y * 128;

    const int wr = w >> 1, wc = w & 1;
    const int fr = lane & 15;
    const int kg = lane >> 4;

    // staging lane constants
    const int aRow  = lane >> 4;                       // row within 4-row chunk
    const int aGranP = (lane & 15) >> 1;               // phys 32B-granule
    const int aHalf = (lane & 1) * 4;                  // 16B half (f32 units)
    const int bRow  = lane >> 3;                       // row within 8-row chunk
    const int bCol  = ((lane & 7) ^ (lane >> 3)) * 8;  // logical col (u16 units)

    f32x4 acc[4][4];
#pragma unroll
    for (int i = 0; i < 4; ++i)
#pragma unroll
        for (int j = 0; j < 4; ++j) acc[i][j] = (f32x4){0.f, 0.f, 0.f, 0.f};

    for (int k0 = 0; k0 < DIN; k0 += 64) {
        // A fp32 tile: 32 chunks x 4 rows; wave w stages chunks w*8..w*8+7
#pragma unroll
        for (int i = 0; i < 8; ++i) {
            const int c = w * 8 + i;
            const int r = c * 4 + aRow;
            const int lg = aGranP ^ (r & 7);           // logical 8-f32 granule
            ld_lds16(X + (size_t)(mBase + r) * DIN + k0 + lg * 8 + aHalf,
                     As + c * 256);
        }
        // B bf16 hi/lo: 16 chunks x 8 rows; wave w stages chunks w*4..w*4+3
#pragma unroll
        for (int i = 0; i < 4; ++i) {
            const int c = w * 4 + i;
            const int r = c * 8 + bRow;
            ld_lds16(Whi + (size_t)(nBase + r) * DIN + k0 + bCol, Bh + c * 512);
            ld_lds16(Wlo + (size_t)(nBase + r) * DIN + k0 + bCol, Bl + c * 512);
        }
        __syncthreads();
#pragma unroll
        for (int ks = 0; ks < 2; ++ks) {
            const int colE = ks * 32 + kg * 8;
            bf16x8 ah[4], al[4], bh[4], bl[4];
#pragma unroll
            for (int f = 0; f < 4; ++f) {
                const int ra = wr * 64 + f * 16 + fr;
                const int pa = ra * 64 + (colE ^ ((fr & 7) << 3));
                const f32x4 v0 = *(const f32x4*)(As + pa);
                const f32x4 v1 = *(const f32x4*)(As + pa + 4);
                bf16x8 h8, l8;
#pragma unroll
                for (int e = 0; e < 4; ++e) {
                    u16 a, b;
                    splitf(v0[e], a, b); h8[e] = (short)a; l8[e] = (short)b;
                    splitf(v1[e], a, b); h8[e + 4] = (short)a; l8[e + 4] = (short)b;
                }
                ah[f] = h8; al[f] = l8;
                const int rb = wc * 64 + f * 16 + fr;
                const int pb = rb * 64 + (colE ^ ((fr & 7) << 3));
                bh[f] = *(const bf16x8*)(Bh + pb);
                bl[f] = *(const bf16x8*)(Bl + pb);
            }
#pragma unroll
            for (int i = 0; i < 4; ++i)
#pragma unroll
                for (int j = 0; j < 4; ++j) {
                    acc[i][j] = __builtin_amdgcn_mfma_f32_16x16x32_bf16(ah[i], bh[j], acc[i][j], 0, 0, 0);
                    acc[i][j] = __builtin_amdgcn_mfma_f32_16x16x32_bf16(ah[i], bl[j], acc[i][j], 0, 0, 0);
                    acc[i][j] = __builtin_amdgcn_mfma_f32_16x16x32_bf16(al[i], bh[j], acc[i][j], 0, 0, 0);
                }
        }
        __syncthreads();
    }

    // epilogue: acc -> scan tile (C/D layout: col=lane&15, row=(lane>>4)*4+rg)
#pragma unroll
    for (int i = 0; i < 4; ++i)
#pragma unroll
        for (int j = 0; j < 4; ++j)
#pragma unroll
            for (int rg = 0; rg < 4; ++rg)
                st[(wr * 64 + i * 16 + kg * 4 + rg) * 132 + wc * 64 + j * 16 + fr]
                    = acc[i][j][rg];
    __syncthreads();

    // local scan along t (tile rows), one column per thread
    if (tid < 128) {
        const float wv = wdiag[nBase + tid];
        float h = 0.f;
#pragma unroll 8
        for (int t = 0; t < 128; ++t) {
            h = fmaf(wv, h, st[t * 132 + tid]);
            st[t * 132 + tid] = h;
        }
        const int c = (mBase >> 7) & (NCHUNK - 1);
        const int b = mBase >> 12;
        L[(c * BATCH + b) * HID + nBase + tid] = h;
    }
    __syncthreads();

    // split + write local state
#pragma unroll
    for (int it = 0; it < 16; ++it) {
        const int idx = it * 256 + tid;
        const int row = idx >> 5, c4 = (idx & 31) * 4;
        const f32x4 v = *(const f32x4*)(st + row * 132 + c4);
        u16x4 hv, lv;
#pragma unroll
        for (int e = 0; e < 4; ++e) { u16 a, b; splitf(v[e], a, b); hv[e] = a; lv[e] = b; }
        const size_t o = (size_t)(mBase + row) * HID + nBase + c4;
        *(u16x4*)(localhi + o) = hv;
        *(u16x4*)(locallo + o) = lv;
    }
}

// ---------------------------------------------------------------------------
// carry across chunks: carry[c][b][h] = state entering chunk c
// ---------------------------------------------------------------------------
__global__ __launch_bounds__(256) void scan_carry(
        const float* __restrict__ L, const float* __restrict__ wpow,
        float* __restrict__ carry) {
    const int idx = blockIdx.x * 256 + threadIdx.x;   // 8192
    const int h = idx & (HID - 1);
    const int b = idx >> 9;
    const float wf = wpow[(CLEN - 1) * HID + h];      // w^128
    float H = 0.f;
    for (int c = 0; c < NCHUNK; ++c) {
        const int o = (c * BATCH + b) * HID + h;
        carry[o] = H;
        H = fmaf(wf, H, L[o]);
    }
}

// ---------------------------------------------------------------------------
// fix + re-split in place: hs = local + w^(tl+1)*carry[c,b]
// (safe in place: each element read+written by exactly one thread; gemm1
//  rewrites local every call, so graph replays are deterministic)
// ---------------------------------------------------------------------------
__global__ __launch_bounds__(256) void fix_convert(
        u16* __restrict__ localhi, u16* __restrict__ locallo,
        const float* __restrict__ wpow, const float* __restrict__ carry) {
    const size_t total4 = (size_t)M_TOT * HID / 4;    // 8388608
    for (size_t e4 = (size_t)blockIdx.x * 256 + threadIdx.x; e4 < total4;
         e4 += (size_t)gridDim.x * 256) {
        const size_t e = e4 * 4;
        const int h = (int)(e & (HID - 1));
        const size_t m = e >> 9;
        const int t = (int)(m & (SEQT - 1));
        const int b = (int)(m >> 12);
        const int c = t >> 7;
        const int tl = t & (CLEN - 1);
        const u16x4 hv = *(const u16x4*)(localhi + e);
        const u16x4 lv = *(const u16x4*)(locallo + e);
        const f32x4 wp = *(const f32x4*)(wpow + (size_t)tl * HID + h);
        const f32x4 cr = *(const f32x4*)(carry + (size_t)(c * BATCH + b) * HID + h);
        u16x4 ho, lo_;
#pragma unroll
        for (int k = 0; k < 4; ++k) {
            float f = bf2f(hv[k]) + bf2f(lv[k]);
            f = fmaf(wp[k], cr[k], f);
            u16 a, b2; splitf(f, a, b2);
            ho[k] = a; lo_[k] = b2;
        }
        *(u16x4*)(localhi + e) = ho;
        *(u16x4*)(locallo + e) = lo_;
    }
}

// ---------------------------------------------------------------------------
// GEMM2: out = hs @ W_out^T, all operands pre-split bf16, pure m97-style
// global_load_lds staging with XOR-swizzle.
// ---------------------------------------------------------------------------
__global__ __launch_bounds__(256, 2) void gemm2(
        const u16* __restrict__ Ahi_g, const u16* __restrict__ Alo_g,
        const u16* __restrict__ Bhi_g, const u16* __restrict__ Blo_g,
        float* __restrict__ C) {
    __shared__ __align__(16) char smem[65536];
    u16* Ah = (u16*)smem;
    u16* Al = (u16*)(smem + 16384);
    u16* Bh = (u16*)(smem + 32768);
    u16* Bl = (u16*)(smem + 49152);

    const int tid  = threadIdx.x;
    const int w    = tid >> 6;
    const int lane = tid & 63;
    const int mBase = blockIdx.x * 128;
    const int nBase = blockIdx.y * 128;

    const int wr = w >> 1, wc = w & 1;
    const int fr = lane & 15;
    const int kg = lane >> 4;

    const int bRow = lane >> 3;
    const int bCol = ((lane & 7) ^ (lane >> 3)) * 8;

    f32x4 acc[4][4];
#pragma unroll
    for (int i = 0; i < 4; ++i)
#pragma unroll
        for (int j = 0; j < 4; ++j) acc[i][j] = (f32x4){0.f, 0.f, 0.f, 0.f};

    for (int k0 = 0; k0 < HID; k0 += 64) {
#pragma unroll
        for (int i = 0; i < 4; ++i) {
            const int c = w * 4 + i;
            const int r = c * 8 + bRow;
            ld_lds16(Ahi_g + (size_t)(mBase + r) * HID + k0 + bCol, Ah + c * 512);
            ld_lds16(Alo_g + (size_t)(mBase + r) * HID + k0 + bCol, Al + c * 512);
            ld_lds16(Bhi_g + (size_t)(nBase + r) * HID + k0 + bCol, Bh + c * 512);
            ld_lds16(Blo_g + (size_t)(nBase + r) * HID + k0 + bCol, Bl + c * 512);
        }
        __syncthreads();
#pragma unroll
        for (int ks = 0; ks < 2; ++ks) {
            const int colE = ks * 32 + kg * 8;
            bf16x8 ah[4], al[4], bh[4], bl[4];
#pragma unroll
            for (int f = 0; f < 4; ++f) {
                const int ra = wr * 64 + f * 16 + fr;
                const int pa = ra * 64 + (colE ^ ((fr & 7) << 3));
                ah[f] = *(const bf16x8*)(Ah + pa);
                al[f] = *(const bf16x8*)(Al + pa);
                const int rb = wc * 64 + f * 16 + fr;
                const int pb = rb * 64 + (colE ^ ((fr & 7) << 3));
                bh[f] = *(const bf16x8*)(Bh + pb);
                bl[f] = *(const bf16x8*)(Bl + pb);
            }
#pragma unroll
            for (int i = 0; i < 4; ++i)
#pragma unroll
                for (int j = 0; j < 4; ++j) {
                    acc[i][j] = __builtin_amdgcn_mfma_f32_16x16x32_bf16(ah[i], bh[j], acc[i][j], 0, 0, 0);
                    acc[i][j] = __builtin_amdgcn_mfma_f32_16x16x32_bf16(ah[i], bl[j], acc[i][j], 0, 0, 0);
                    acc[i][j] = __builtin_amdgcn_mfma_f32_16x16x32_bf16(al[i], bh[j], acc[i][j], 0, 0, 0);
                }
        }
        __syncthreads();
    }

#pragma unroll
    for (int i = 0; i < 4; ++i) {
        const size_t row0 = (size_t)mBase + wr * 64 + i * 16 + kg * 4;
#pragma unroll
        for (int j = 0; j < 4; ++j) {
            const int col = nBase + wc * 64 + j * 16 + fr;
#pragma unroll
            for (int rg = 0; rg < 4; ++rg)
                C[(row0 + rg) * DOUT + col] = acc[i][j][rg];
        }
    }
}

// ---------------------------------------------------------------------------
extern "C" void kernel_launch(void* const* d_in, const int* in_sizes, int n_in,
                              void* d_out, int out_size, void* d_ws, size_t ws_size,
                              hipStream_t stream) {
    const float* x     = (const float*)d_in[0];   // [16,4096,256]
    const float* W_in  = (const float*)d_in[1];   // [512,256]
    const float* W_h   = (const float*)d_in[2];   // [512,512] (diagonal)
    const float* W_out = (const float*)d_in[3];   // [256,512]
    float* out = (float*)d_out;                    // [16,4096,256]

    // workspace layout (137,627,648 B total)
    char* ws = (char*)d_ws;
    u16*   localhi = (u16*)(ws);                       // 67,108,864
    u16*   locallo = (u16*)(ws + 67108864);            // 67,108,864
    float* L       = (float*)(ws + 134217728);         // 1,048,576
    float* carry   = (float*)(ws + 135266304);         // 1,048,576
    float* wpow    = (float*)(ws + 136314880);         // 262,144
    float* wdiag   = (float*)(ws + 136577024);         // 2,048
    u16*   Winhi   = (u16*)(ws + 136579072);           // 262,144
    u16*   Winlo   = (u16*)(ws + 136841216);           // 262,144
    u16*   Wouthi  = (u16*)(ws + 137103360);           // 262,144
    u16*   Woutlo  = (u16*)(ws + 137365504);           // 262,144

    prep<<<257, 256, 0, stream>>>(W_h, W_in, W_out, wdiag, wpow,
                                  Winhi, Winlo, Wouthi, Woutlo);
    gemm1_scan<<<dim3(M_TOT / 128, HID / 128), 256, 0, stream>>>(
        x, Winhi, Winlo, localhi, locallo, L, wdiag);
    scan_carry<<<32, 256, 0, stream>>>(L, wpow, carry);
    fix_convert<<<2048, 256, 0, stream>>>(localhi, locallo, wpow, carry);
    gemm2<<<dim3(M_TOT / 128, DOUT / 128), 256, 0, stream>>>(
        localhi, locallo, Wouthi, Woutlo, out);
}

// Round 4
// 158.179 us; speedup vs baseline: 3.3973x; 1.2628x over previous
//
#include <hip/hip_runtime.h>
#include <hip/hip_bf16.h>
#include <stdint.h>

// Problem constants (LinearRNN): B=16, T=4096, D_IN=256, HID=512, D_OUT=256
#define BATCH 16
#define SEQT  4096
#define DIN   256
#define HID   512
#define DOUT  256
#define M_TOT 65536
#define CLEN  128                 // chunk length (== GEMM m-tile)
#define NCHUNK 32                 // SEQT / CLEN

typedef short bf16x8 __attribute__((ext_vector_type(8)));
typedef float f32x4  __attribute__((ext_vector_type(4)));
typedef unsigned short u16;
typedef unsigned short u16x4 __attribute__((ext_vector_type(4)));
typedef unsigned int uint32;

// async global->LDS, 16B per lane; LDS dest is wave-uniform base + lane*16
__device__ __forceinline__ void ld_lds16(const void* g, void* l) {
    __builtin_amdgcn_global_load_lds(
        (const __attribute__((address_space(1))) void*)g,
        (__attribute__((address_space(3))) void*)l, 16, 0, 0);
}

__device__ __forceinline__ u16 f2bf_rne(float f) {
    uint32 v = __float_as_uint(f);
    v += 0x7FFFu + ((v >> 16) & 1u);
    return (u16)(v >> 16);
}

// trunc-hi / rne-lo split: f ~= hi + lo, ~17-bit combined mantissa
__device__ __forceinline__ void splitf(float f, u16& hi, u16& lo) {
    const uint32 u = __float_as_uint(f);
    hi = (u16)(u >> 16);
    lo = f2bf_rne(f - __uint_as_float(u & 0xFFFF0000u));
}

// ---------------------------------------------------------------------------
// prep: block 0 -> wdiag + wpow (w^(tl+1), tl<128); blocks 1..128 -> W_in
// split; blocks 129..256 -> W_out split.
// ---------------------------------------------------------------------------
__global__ __launch_bounds__(256) void prep(
        const float* __restrict__ Wh, const float* __restrict__ Win,
        const float* __restrict__ Wout, float* __restrict__ wdiag,
        float* __restrict__ wpow, u16* __restrict__ Winhi,
        u16* __restrict__ Winlo, u16* __restrict__ Wouthi,
        u16* __restrict__ Woutlo) {
    const int bid = blockIdx.x, tid = threadIdx.x;
    if (bid == 0) {
        for (int h = tid; h < HID; h += 256) {
            const float wv = Wh[(size_t)h * HID + h];
            wdiag[h] = wv;
            float p = 1.f;
            for (int t = 0; t < CLEN; ++t) { p *= wv; wpow[t * HID + h] = p; }
        }
    } else if (bid <= 128) {
        const int f4 = (bid - 1) * 256 + tid;   // < 32768
        const f32x4 v = *(const f32x4*)(Win + (size_t)f4 * 4);
        u16x4 hv, lv;
#pragma unroll
        for (int k = 0; k < 4; ++k) { u16 a, b; splitf(v[k], a, b); hv[k] = a; lv[k] = b; }
        *(u16x4*)(Winhi + (size_t)f4 * 4) = hv;
        *(u16x4*)(Winlo + (size_t)f4 * 4) = lv;
    } else {
        const int f4 = (bid - 129) * 256 + tid;
        const f32x4 v = *(const f32x4*)(Wout + (size_t)f4 * 4);
        u16x4 hv, lv;
#pragma unroll
        for (int k = 0; k < 4; ++k) { u16 a, b; splitf(v[k], a, b); hv[k] = a; lv[k] = b; }
        *(u16x4*)(Wouthi + (size_t)f4 * 4) = hv;
        *(u16x4*)(Woutlo + (size_t)f4 * 4) = lv;
    }
}

// ---------------------------------------------------------------------------
// GEMM1 + fused segmented scan: xp = x @ W_in^T per 128x128 tile (tile rows
// == one full chunk), then scan along t with a 3-phase segmented scan
// (registers + tiny LDS), write fp32 chunk-local state + chunk-final L.
// Grid: 2048 linear, XCD-swizzled (xcd = bid&7 owns a contiguous m-run).
// ---------------------------------------------------------------------------
__global__ __launch_bounds__(256, 2) void gemm1_scan(
        const float* __restrict__ X, const u16* __restrict__ Whi,
        const u16* __restrict__ Wlo, float* __restrict__ localo,
        float* __restrict__ L, const float* __restrict__ wdiag,
        const float* __restrict__ wpow) {
    __shared__ __align__(16) char smem[75776];
    float* As = (float*)smem;               // [32 chunks][256 f32], swizzled (32KB)
    u16*   Bh = (u16*)(smem + 32768);       // [128][64] bf16, swizzled (16KB)
    u16*   Bl = (u16*)(smem + 49152);       // 16KB
    float* st = (float*)smem;               // scan tile [128][132] f32 (aliased, 66KB)
    float* segT = (float*)(smem + 67584);   // [8][128] seg totals (4KB)
    float* segC = (float*)(smem + 71680);   // [8][128] seg carries (4KB)

    const int tid  = threadIdx.x;
    const int w    = tid >> 6;
    const int lane = tid & 63;

    // XCD swizzle: 8 XCDs x 256 slots; slot = (m within xcd-run, n)
    const int bid  = blockIdx.x;
    const int xcd  = bid & 7;
    const int slot = bid >> 3;              // 0..255
    const int mBase = (xcd * 64 + (slot >> 2)) * 128;
    const int nBase = (slot & 3) * 128;

    const int wr = w >> 1, wc = w & 1;
    const int fr = lane & 15;
    const int kg = lane >> 4;

    // staging lane constants
    const int aRow   = lane >> 4;                      // row within 4-row chunk
    const int aGranP = (lane & 15) >> 1;               // phys 32B-granule
    const int aHalf  = (lane & 1) * 4;                 // 16B half (f32 units)
    const int bRow   = lane >> 3;                      // row within 8-row chunk
    const int bCol   = ((lane & 7) ^ (lane >> 3)) * 8; // logical col (u16 units)

    f32x4 acc[4][4];
#pragma unroll
    for (int i = 0; i < 4; ++i)
#pragma unroll
        for (int j = 0; j < 4; ++j) acc[i][j] = (f32x4){0.f, 0.f, 0.f, 0.f};

    for (int k0 = 0; k0 < DIN; k0 += 64) {
        // A fp32 tile: 32 chunks x 4 rows; wave w stages chunks w*8..w*8+7
#pragma unroll
        for (int i = 0; i < 8; ++i) {
            const int c = w * 8 + i;
            const int r = c * 4 + aRow;
            const int lg = aGranP ^ (r & 7);           // logical 8-f32 granule
            ld_lds16(X + (size_t)(mBase + r) * DIN + k0 + lg * 8 + aHalf,
                     As + c * 256);
        }
        // B bf16 hi/lo: 16 chunks x 8 rows; wave w stages chunks w*4..w*4+3
#pragma unroll
        for (int i = 0; i < 4; ++i) {
            const int c = w * 4 + i;
            const int r = c * 8 + bRow;
            ld_lds16(Whi + (size_t)(nBase + r) * DIN + k0 + bCol, Bh + c * 512);
            ld_lds16(Wlo + (size_t)(nBase + r) * DIN + k0 + bCol, Bl + c * 512);
        }
        __syncthreads();
#pragma unroll
        for (int ks = 0; ks < 2; ++ks) {
            const int colE = ks * 32 + kg * 8;
            bf16x8 ah[4], al[4], bh[4], bl[4];
#pragma unroll
            for (int f = 0; f < 4; ++f) {
                const int ra = wr * 64 + f * 16 + fr;
                const int pa = ra * 64 + (colE ^ ((fr & 7) << 3));
                const f32x4 v0 = *(const f32x4*)(As + pa);
                const f32x4 v1 = *(const f32x4*)(As + pa + 4);
                bf16x8 h8, l8;
#pragma unroll
                for (int e = 0; e < 4; ++e) {
                    u16 a, b;
                    splitf(v0[e], a, b); h8[e] = (short)a; l8[e] = (short)b;
                    splitf(v1[e], a, b); h8[e + 4] = (short)a; l8[e + 4] = (short)b;
                }
                ah[f] = h8; al[f] = l8;
                const int rb = wc * 64 + f * 16 + fr;
                const int pb = rb * 64 + (colE ^ ((fr & 7) << 3));
                bh[f] = *(const bf16x8*)(Bh + pb);
                bl[f] = *(const bf16x8*)(Bl + pb);
            }
#pragma unroll
            for (int i = 0; i < 4; ++i)
#pragma unroll
                for (int j = 0; j < 4; ++j) {
                    acc[i][j] = __builtin_amdgcn_mfma_f32_16x16x32_bf16(ah[i], bh[j], acc[i][j], 0, 0, 0);
                    acc[i][j] = __builtin_amdgcn_mfma_f32_16x16x32_bf16(ah[i], bl[j], acc[i][j], 0, 0, 0);
                    acc[i][j] = __builtin_amdgcn_mfma_f32_16x16x32_bf16(al[i], bh[j], acc[i][j], 0, 0, 0);
                }
        }
        __syncthreads();
    }

    // epilogue: acc -> scan tile (C/D layout: col=lane&15, row=(lane>>4)*4+rg)
#pragma unroll
    for (int i = 0; i < 4; ++i)
#pragma unroll
        for (int j = 0; j < 4; ++j)
#pragma unroll
            for (int rg = 0; rg < 4; ++rg)
                st[(wr * 64 + i * 16 + kg * 4 + rg) * 132 + wc * 64 + j * 16 + fr]
                    = acc[i][j][rg];
    __syncthreads();

    // --- segmented scan along t: 8 segments of 16 rows ---
    // phase 1: thread (hcol, sh) scans 4 segments in registers
    const int hcol = tid & 127;
    const int sh   = tid >> 7;          // 0 or 1 (segments sh*4 .. sh*4+3)
    const float wv = wdiag[nBase + hcol];
    float rr[4][16];
#pragma unroll
    for (int s = 0; s < 4; ++s) {
        float run = 0.f;
#pragma unroll
        for (int i = 0; i < 16; ++i) {
            run = fmaf(wv, run, st[((sh * 4 + s) * 16 + i) * 132 + hcol]);
            rr[s][i] = run;
        }
        segT[(sh * 4 + s) * 128 + hcol] = run;
    }
    __syncthreads();
    // phase 2: scan the 8 segment totals (factor w^16), emit carries + L
    if (tid < 128) {
        const float w16 = wpow[15 * HID + nBase + tid];   // w^16
        float c = 0.f;
#pragma unroll
        for (int s = 0; s < 8; ++s) {
            segC[s * 128 + tid] = c;
            c = fmaf(w16, c, segT[s * 128 + tid]);
        }
        const int cI = (mBase >> 7) & (NCHUNK - 1);
        const int bI = mBase >> 12;
        L[(cI * BATCH + bI) * HID + nBase + tid] = c;     // chunk-final
    }
    __syncthreads();
    // phase 3: apply segment carry, write fp32 chunk-local state
#pragma unroll
    for (int s = 0; s < 4; ++s) {
        const float cin = segC[(sh * 4 + s) * 128 + hcol];
        float p = wv;
        float* dst = localo + (size_t)(mBase + (sh * 4 + s) * 16) * HID + nBase + hcol;
#pragma unroll
        for (int i = 0; i < 16; ++i) {
            dst[(size_t)i * HID] = fmaf(p, cin, rr[s][i]);
            p *= wv;
        }
    }
}

// ---------------------------------------------------------------------------
// carry across chunks: carry[c][b][h] = state entering chunk c
// ---------------------------------------------------------------------------
__global__ __launch_bounds__(256) void scan_carry(
        const float* __restrict__ L, const float* __restrict__ wpow,
        float* __restrict__ carry) {
    const int idx = blockIdx.x * 256 + threadIdx.x;   // 8192
    const int h = idx & (HID - 1);
    const int b = idx >> 9;
    const float wf = wpow[(CLEN - 1) * HID + h];      // w^128
    float H = 0.f;
    for (int c = 0; c < NCHUNK; ++c) {
        const int o = (c * BATCH + b) * HID + h;
        carry[o] = H;
        H = fmaf(wf, H, L[o]);
    }
}

// ---------------------------------------------------------------------------
// GEMM2 with fused fix: out = (local + w^(tl+1)*carry) @ W_out^T.
// A reg-staged: load fp32 local, apply fix, split to bf16 hi/lo, ds_write
// swizzled. B pre-split bf16 via global_load_lds.
// Grid: 1024 linear, XCD-swizzled.
// ---------------------------------------------------------------------------
__global__ __launch_bounds__(256, 2) void gemm2_fix(
        const float* __restrict__ localo, const u16* __restrict__ Bhi_g,
        const u16* __restrict__ Blo_g, const float* __restrict__ wpow,
        const float* __restrict__ carry, float* __restrict__ C) {
    __shared__ __align__(16) char smem[65536];
    u16* Ah = (u16*)smem;                   // [128][64] swizzled (16KB)
    u16* Al = (u16*)(smem + 16384);
    u16* Bh = (u16*)(smem + 32768);
    u16* Bl = (u16*)(smem + 49152);

    const int tid  = threadIdx.x;
    const int w    = tid >> 6;
    const int lane = tid & 63;

    const int bid  = blockIdx.x;
    const int xcd  = bid & 7;
    const int slot = bid >> 3;              // 0..127
    const int mBase = (xcd * 64 + (slot >> 1)) * 128;
    const int nBase = (slot & 1) * 128;

    const int wr = w >> 1, wc = w & 1;
    const int fr = lane & 15;
    const int kg = lane >> 4;

    const int bRow = lane >> 3;
    const int bCol = ((lane & 7) ^ bRow) * 8;

    // fix constants: whole m-tile is one (chunk, batch)
    const int cI = (mBase >> 7) & (NCHUNK - 1);
    const int bI = mBase >> 12;
    const float* crow = carry + (size_t)(cI * BATCH + bI) * HID;

    f32x4 acc[4][4];
#pragma unroll
    for (int i = 0; i < 4; ++i)
#pragma unroll
        for (int j = 0; j < 4; ++j) acc[i][j] = (f32x4){0.f, 0.f, 0.f, 0.f};

    for (int k0 = 0; k0 < HID; k0 += 64) {
        // A: reg-staged, fix + split fused
#pragma unroll
        for (int it = 0; it < 4; ++it) {
            const int idx = it * 256 + tid;   // 0..1023 granules
            const int r  = idx >> 3;          // 0..127
            const int gl = idx & 7;           // logical 8-f32 granule
            const int gm = mBase + r;
            const int tl = gm & (CLEN - 1);
            const size_t col = (size_t)(k0 + gl * 8);
            f32x4 v0 = *(const f32x4*)(localo + (size_t)gm * HID + col);
            f32x4 v1 = *(const f32x4*)(localo + (size_t)gm * HID + col + 4);
            const f32x4 p0 = *(const f32x4*)(wpow + (size_t)tl * HID + col);
            const f32x4 p1 = *(const f32x4*)(wpow + (size_t)tl * HID + col + 4);
            const f32x4 c0 = *(const f32x4*)(crow + col);
            const f32x4 c1 = *(const f32x4*)(crow + col + 4);
            bf16x8 h8, l8;
#pragma unroll
            for (int e = 0; e < 4; ++e) {
                const float f0 = fmaf(p0[e], c0[e], v0[e]);
                const float f1 = fmaf(p1[e], c1[e], v1[e]);
                u16 a, b;
                splitf(f0, a, b); h8[e] = (short)a; l8[e] = (short)b;
                splitf(f1, a, b); h8[e + 4] = (short)a; l8[e + 4] = (short)b;
            }
            const int phys = r * 64 + ((gl ^ (r & 7)) * 8);
            *(bf16x8*)(Ah + phys) = h8;
            *(bf16x8*)(Al + phys) = l8;
        }
        // B: async global->LDS (pre-split, pre-swizzled source col)
#pragma unroll
        for (int i = 0; i < 4; ++i) {
            const int c = w * 4 + i;
            const int r2 = c * 8 + bRow;
            ld_lds16(Bhi_g + (size_t)(nBase + r2) * HID + k0 + bCol, Bh + c * 512);
            ld_lds16(Blo_g + (size_t)(nBase + r2) * HID + k0 + bCol, Bl + c * 512);
        }
        __syncthreads();
#pragma unroll
        for (int ks = 0; ks < 2; ++ks) {
            const int colE = ks * 32 + kg * 8;
            bf16x8 ah[4], al[4], bh[4], bl[4];
#pragma unroll
            for (int f = 0; f < 4; ++f) {
                const int ra = wr * 64 + f * 16 + fr;
                const int pa = ra * 64 + (colE ^ ((fr & 7) << 3));
                ah[f] = *(const bf16x8*)(Ah + pa);
                al[f] = *(const bf16x8*)(Al + pa);
                const int rb = wc * 64 + f * 16 + fr;
                const int pb = rb * 64 + (colE ^ ((fr & 7) << 3));
                bh[f] = *(const bf16x8*)(Bh + pb);
                bl[f] = *(const bf16x8*)(Bl + pb);
            }
#pragma unroll
            for (int i = 0; i < 4; ++i)
#pragma unroll
                for (int j = 0; j < 4; ++j) {
                    acc[i][j] = __builtin_amdgcn_mfma_f32_16x16x32_bf16(ah[i], bh[j], acc[i][j], 0, 0, 0);
                    acc[i][j] = __builtin_amdgcn_mfma_f32_16x16x32_bf16(ah[i], bl[j], acc[i][j], 0, 0, 0);
                    acc[i][j] = __builtin_amdgcn_mfma_f32_16x16x32_bf16(al[i], bh[j], acc[i][j], 0, 0, 0);
                }
        }
        __syncthreads();
    }

#pragma unroll
    for (int i = 0; i < 4; ++i) {
        const size_t row0 = (size_t)mBase + wr * 64 + i * 16 + kg * 4;
#pragma unroll
        for (int j = 0; j < 4; ++j) {
            const int col = nBase + wc * 64 + j * 16 + fr;
#pragma unroll
            for (int rg = 0; rg < 4; ++rg)
                C[(row0 + rg) * DOUT + col] = acc[i][j][rg];
        }
    }
}

// ---------------------------------------------------------------------------
extern "C" void kernel_launch(void* const* d_in, const int* in_sizes, int n_in,
                              void* d_out, int out_size, void* d_ws, size_t ws_size,
                              hipStream_t stream) {
    const float* x     = (const float*)d_in[0];   // [16,4096,256]
    const float* W_in  = (const float*)d_in[1];   // [512,256]
    const float* W_h   = (const float*)d_in[2];   // [512,512] (diagonal)
    const float* W_out = (const float*)d_in[3];   // [256,512]
    float* out = (float*)d_out;                    // [16,4096,256]

    // workspace layout (137,627,648 B total)
    char* ws = (char*)d_ws;
    float* localo = (float*)(ws);                      // 134,217,728 (fp32 local state)
    float* L      = (float*)(ws + 134217728);          // 1,048,576
    float* carry  = (float*)(ws + 135266304);          // 1,048,576
    float* wpow   = (float*)(ws + 136314880);          // 262,144
    float* wdiag  = (float*)(ws + 136577024);          // 2,048
    u16*   Winhi  = (u16*)(ws + 136579072);            // 262,144
    u16*   Winlo  = (u16*)(ws + 136841216);            // 262,144
    u16*   Wouthi = (u16*)(ws + 137103360);            // 262,144
    u16*   Woutlo = (u16*)(ws + 137365504);            // 262,144

    prep<<<257, 256, 0, stream>>>(W_h, W_in, W_out, wdiag, wpow,
                                  Winhi, Winlo, Wouthi, Woutlo);
    gemm1_scan<<<2048, 256, 0, stream>>>(x, Winhi, Winlo, localo, L, wdiag, wpow);
    scan_carry<<<32, 256, 0, stream>>>(L, wpow, carry);
    gemm2_fix<<<1024, 256, 0, stream>>>(localo, Wouthi, Woutlo, wpow, carry, out);
}

// Round 5
// 142.350 us; speedup vs baseline: 3.7750x; 1.1112x over previous
//
#include <hip/hip_runtime.h>
#include <hip/hip_bf16.h>
#include <stdint.h>

// Problem constants (LinearRNN): B=16, T=4096, D_IN=256, HID=512, D_OUT=256
#define BATCH 16
#define SEQT  4096
#define DIN   256
#define HID   512
#define DOUT  256
#define M_TOT 65536
#define CLEN  128                 // chunk length (== GEMM m-tile)
#define NCHUNK 32                 // SEQT / CLEN

typedef short bf16x8 __attribute__((ext_vector_type(8)));
typedef float f32x4  __attribute__((ext_vector_type(4)));
typedef unsigned short u16;
typedef unsigned short u16x4 __attribute__((ext_vector_type(4)));
typedef unsigned int uint32;

// async global->LDS, 16B per lane; LDS dest is wave-uniform base + lane*16
__device__ __forceinline__ void ld_lds16(const void* g, void* l) {
    __builtin_amdgcn_global_load_lds(
        (const __attribute__((address_space(1))) void*)g,
        (__attribute__((address_space(3))) void*)l, 16, 0, 0);
}

__device__ __forceinline__ u16 f2bf_rne(float f) {
    uint32 v = __float_as_uint(f);
    v += 0x7FFFu + ((v >> 16) & 1u);
    return (u16)(v >> 16);
}

// trunc-hi / rne-lo split: f ~= hi + lo, ~17-bit combined mantissa
__device__ __forceinline__ void splitf(float f, u16& hi, u16& lo) {
    const uint32 u = __float_as_uint(f);
    hi = (u16)(u >> 16);
    lo = f2bf_rne(f - __uint_as_float(u & 0xFFFF0000u));
}

// ---------------------------------------------------------------------------
// prep: block 0 -> wdiag + wpow (w^(tl+1), tl<128); blocks 1..128 -> W_in
// split; blocks 129..256 -> W_out split.
// ---------------------------------------------------------------------------
__global__ __launch_bounds__(256) void prep(
        const float* __restrict__ Wh, const float* __restrict__ Win,
        const float* __restrict__ Wout, float* __restrict__ wdiag,
        float* __restrict__ wpow, u16* __restrict__ Winhi,
        u16* __restrict__ Winlo, u16* __restrict__ Wouthi,
        u16* __restrict__ Woutlo) {
    const int bid = blockIdx.x, tid = threadIdx.x;
    if (bid == 0) {
        for (int h = tid; h < HID; h += 256) {
            const float wv = Wh[(size_t)h * HID + h];
            wdiag[h] = wv;
            float p = 1.f;
            for (int t = 0; t < CLEN; ++t) { p *= wv; wpow[t * HID + h] = p; }
        }
    } else if (bid <= 128) {
        const int f4 = (bid - 1) * 256 + tid;   // < 32768
        const f32x4 v = *(const f32x4*)(Win + (size_t)f4 * 4);
        u16x4 hv, lv;
#pragma unroll
        for (int k = 0; k < 4; ++k) { u16 a, b; splitf(v[k], a, b); hv[k] = a; lv[k] = b; }
        *(u16x4*)(Winhi + (size_t)f4 * 4) = hv;
        *(u16x4*)(Winlo + (size_t)f4 * 4) = lv;
    } else {
        const int f4 = (bid - 129) * 256 + tid;
        const f32x4 v = *(const f32x4*)(Wout + (size_t)f4 * 4);
        u16x4 hv, lv;
#pragma unroll
        for (int k = 0; k < 4; ++k) { u16 a, b; splitf(v[k], a, b); hv[k] = a; lv[k] = b; }
        *(u16x4*)(Wouthi + (size_t)f4 * 4) = hv;
        *(u16x4*)(Woutlo + (size_t)f4 * 4) = lv;
    }
}

// ---------------------------------------------------------------------------
// GEMM1 + fused segmented scan: xp = x @ W_in^T per 128x128 tile (tile rows
// == one full chunk), then 3-phase segmented scan, write fp32 chunk-local
// state + chunk-final L.
// A-path: reg-staged (global f32 -> split once -> swizzled ds_write), B-path
// global_load_lds issued FIRST so its HBM latency hides under A staging.
// Grid: 2048 linear, XCD-swizzled.
// ---------------------------------------------------------------------------
__global__ __launch_bounds__(256, 2) void gemm1_scan(
        const float* __restrict__ X, const u16* __restrict__ Whi,
        const u16* __restrict__ Wlo, float* __restrict__ localo,
        float* __restrict__ L, const float* __restrict__ wdiag,
        const float* __restrict__ wpow) {
    __shared__ __align__(16) char smem[75776];
    u16*   Ah = (u16*)smem;                 // [128][64] bf16 hi, swizzled (16KB)
    u16*   Al = (u16*)(smem + 16384);       // lo (16KB)
    u16*   Bh = (u16*)(smem + 32768);       // [128][64] bf16, swizzled (16KB)
    u16*   Bl = (u16*)(smem + 49152);       // 16KB
    float* st = (float*)smem;               // scan tile [128][132] f32 (aliased, 66KB)
    float* segT = (float*)(smem + 67584);   // [8][128] seg totals (4KB)
    float* segC = (float*)(smem + 71680);   // [8][128] seg carries (4KB)

    const int tid  = threadIdx.x;
    const int w    = tid >> 6;
    const int lane = tid & 63;

    // XCD swizzle: 8 XCDs x 256 slots; slot = (m within xcd-run, n)
    const int bid  = blockIdx.x;
    const int xcd  = bid & 7;
    const int slot = bid >> 3;              // 0..255
    const int mBase = (xcd * 64 + (slot >> 2)) * 128;
    const int nBase = (slot & 3) * 128;

    const int wr = w >> 1, wc = w & 1;
    const int fr = lane & 15;
    const int kg = lane >> 4;

    const int bRow = lane >> 3;                        // row within 8-row chunk
    const int bCol = ((lane & 7) ^ bRow) * 8;          // pre-swizzled col (u16)

    f32x4 acc[4][4];
#pragma unroll
    for (int i = 0; i < 4; ++i)
#pragma unroll
        for (int j = 0; j < 4; ++j) acc[i][j] = (f32x4){0.f, 0.f, 0.f, 0.f};

    for (int k0 = 0; k0 < DIN; k0 += 64) {
        // B bf16 hi/lo FIRST (async; latency hides under A staging below)
#pragma unroll
        for (int i = 0; i < 4; ++i) {
            const int c = w * 4 + i;
            const int r = c * 8 + bRow;
            ld_lds16(Whi + (size_t)(nBase + r) * DIN + k0 + bCol, Bh + c * 512);
            ld_lds16(Wlo + (size_t)(nBase + r) * DIN + k0 + bCol, Bl + c * 512);
        }
        // A: reg-staged, split once per element, swizzled ds_write
#pragma unroll
        for (int it = 0; it < 4; ++it) {
            const int idx = it * 256 + tid;   // granule of 8 f32
            const int r  = idx >> 3;          // 0..127
            const int gl = idx & 7;
            const float* src = X + (size_t)(mBase + r) * DIN + k0 + gl * 8;
            const f32x4 v0 = *(const f32x4*)(src);
            const f32x4 v1 = *(const f32x4*)(src + 4);
            bf16x8 h8, l8;
#pragma unroll
            for (int e = 0; e < 4; ++e) {
                u16 a, b;
                splitf(v0[e], a, b); h8[e] = (short)a; l8[e] = (short)b;
                splitf(v1[e], a, b); h8[e + 4] = (short)a; l8[e + 4] = (short)b;
            }
            const int phys = r * 64 + ((gl ^ (r & 7)) * 8);
            *(bf16x8*)(Ah + phys) = h8;
            *(bf16x8*)(Al + phys) = l8;
        }
        __syncthreads();
#pragma unroll
        for (int ks = 0; ks < 2; ++ks) {
            const int colE = ks * 32 + kg * 8;
            bf16x8 ah[4], al[4], bh[4], bl[4];
#pragma unroll
            for (int f = 0; f < 4; ++f) {
                const int ra = wr * 64 + f * 16 + fr;
                const int pa = ra * 64 + (colE ^ ((fr & 7) << 3));
                ah[f] = *(const bf16x8*)(Ah + pa);
                al[f] = *(const bf16x8*)(Al + pa);
                const int rb = wc * 64 + f * 16 + fr;
                const int pb = rb * 64 + (colE ^ ((fr & 7) << 3));
                bh[f] = *(const bf16x8*)(Bh + pb);
                bl[f] = *(const bf16x8*)(Bl + pb);
            }
#pragma unroll
            for (int i = 0; i < 4; ++i)
#pragma unroll
                for (int j = 0; j < 4; ++j) {
                    acc[i][j] = __builtin_amdgcn_mfma_f32_16x16x32_bf16(ah[i], bh[j], acc[i][j], 0, 0, 0);
                    acc[i][j] = __builtin_amdgcn_mfma_f32_16x16x32_bf16(ah[i], bl[j], acc[i][j], 0, 0, 0);
                    acc[i][j] = __builtin_amdgcn_mfma_f32_16x16x32_bf16(al[i], bh[j], acc[i][j], 0, 0, 0);
                }
        }
        __syncthreads();
    }

    // epilogue: acc -> scan tile (C/D layout: col=lane&15, row=(lane>>4)*4+rg)
#pragma unroll
    for (int i = 0; i < 4; ++i)
#pragma unroll
        for (int j = 0; j < 4; ++j)
#pragma unroll
            for (int rg = 0; rg < 4; ++rg)
                st[(wr * 64 + i * 16 + kg * 4 + rg) * 132 + wc * 64 + j * 16 + fr]
                    = acc[i][j][rg];
    __syncthreads();

    // --- segmented scan along t: 8 segments of 16 rows ---
    // phase 1: thread (hcol, sh) scans 4 segments in registers
    const int hcol = tid & 127;
    const int sh   = tid >> 7;          // 0 or 1 (segments sh*4 .. sh*4+3)
    const float wv = wdiag[nBase + hcol];
    float rr[4][16];
#pragma unroll
    for (int s = 0; s < 4; ++s) {
        float run = 0.f;
#pragma unroll
        for (int i = 0; i < 16; ++i) {
            run = fmaf(wv, run, st[((sh * 4 + s) * 16 + i) * 132 + hcol]);
            rr[s][i] = run;
        }
        segT[(sh * 4 + s) * 128 + hcol] = run;
    }
    __syncthreads();
    // phase 2: scan the 8 segment totals (factor w^16), emit carries + L
    if (tid < 128) {
        const float w16 = wpow[15 * HID + nBase + tid];   // w^16
        float c = 0.f;
#pragma unroll
        for (int s = 0; s < 8; ++s) {
            segC[s * 128 + tid] = c;
            c = fmaf(w16, c, segT[s * 128 + tid]);
        }
        const int cI = (mBase >> 7) & (NCHUNK - 1);
        const int bI = mBase >> 12;
        L[(cI * BATCH + bI) * HID + nBase + tid] = c;     // chunk-final
    }
    __syncthreads();
    // phase 3: apply segment carry, write fp32 chunk-local state
#pragma unroll
    for (int s = 0; s < 4; ++s) {
        const float cin = segC[(sh * 4 + s) * 128 + hcol];
        float p = wv;
        float* dst = localo + (size_t)(mBase + (sh * 4 + s) * 16) * HID + nBase + hcol;
#pragma unroll
        for (int i = 0; i < 16; ++i) {
            dst[(size_t)i * HID] = fmaf(p, cin, rr[s][i]);
            p *= wv;
        }
    }
}

// ---------------------------------------------------------------------------
// carry across chunks: carry[c][b][h] = state entering chunk c
// ---------------------------------------------------------------------------
__global__ __launch_bounds__(256) void scan_carry(
        const float* __restrict__ L, const float* __restrict__ wpow,
        float* __restrict__ carry) {
    const int idx = blockIdx.x * 256 + threadIdx.x;   // 8192
    const int h = idx & (HID - 1);
    const int b = idx >> 9;
    const float wf = wpow[(CLEN - 1) * HID + h];      // w^128
    float H = 0.f;
    for (int c = 0; c < NCHUNK; ++c) {
        const int o = (c * BATCH + b) * HID + h;
        carry[o] = H;
        H = fmaf(wf, H, L[o]);
    }
}

// ---------------------------------------------------------------------------
// GEMM2 with fused fix: out = (local + w^(tl+1)*carry) @ W_out^T.
// B global_load_lds issued first; A reg-staged with fix + split fused.
// Grid: 1024 linear, XCD-swizzled.
// ---------------------------------------------------------------------------
__global__ __launch_bounds__(256, 2) void gemm2_fix(
        const float* __restrict__ localo, const u16* __restrict__ Bhi_g,
        const u16* __restrict__ Blo_g, const float* __restrict__ wpow,
        const float* __restrict__ carry, float* __restrict__ C) {
    __shared__ __align__(16) char smem[65536];
    u16* Ah = (u16*)smem;                   // [128][64] swizzled (16KB)
    u16* Al = (u16*)(smem + 16384);
    u16* Bh = (u16*)(smem + 32768);
    u16* Bl = (u16*)(smem + 49152);

    const int tid  = threadIdx.x;
    const int w    = tid >> 6;
    const int lane = tid & 63;

    const int bid  = blockIdx.x;
    const int xcd  = bid & 7;
    const int slot = bid >> 3;              // 0..127
    const int mBase = (xcd * 64 + (slot >> 1)) * 128;
    const int nBase = (slot & 1) * 128;

    const int wr = w >> 1, wc = w & 1;
    const int fr = lane & 15;
    const int kg = lane >> 4;

    const int bRow = lane >> 3;
    const int bCol = ((lane & 7) ^ bRow) * 8;

    // fix constants: whole m-tile is one (chunk, batch)
    const int cI = (mBase >> 7) & (NCHUNK - 1);
    const int bI = mBase >> 12;
    const float* crow = carry + (size_t)(cI * BATCH + bI) * HID;

    f32x4 acc[4][4];
#pragma unroll
    for (int i = 0; i < 4; ++i)
#pragma unroll
        for (int j = 0; j < 4; ++j) acc[i][j] = (f32x4){0.f, 0.f, 0.f, 0.f};

    for (int k0 = 0; k0 < HID; k0 += 64) {
        // B: async global->LDS FIRST (latency hides under A staging)
#pragma unroll
        for (int i = 0; i < 4; ++i) {
            const int c = w * 4 + i;
            const int r2 = c * 8 + bRow;
            ld_lds16(Bhi_g + (size_t)(nBase + r2) * HID + k0 + bCol, Bh + c * 512);
            ld_lds16(Blo_g + (size_t)(nBase + r2) * HID + k0 + bCol, Bl + c * 512);
        }
        // A: reg-staged, fix + split fused
#pragma unroll
        for (int it = 0; it < 4; ++it) {
            const int idx = it * 256 + tid;   // 0..1023 granules
            const int r  = idx >> 3;          // 0..127
            const int gl = idx & 7;           // logical 8-f32 granule
            const int gm = mBase + r;
            const int tl = gm & (CLEN - 1);
            const size_t col = (size_t)(k0 + gl * 8);
            f32x4 v0 = *(const f32x4*)(localo + (size_t)gm * HID + col);
            f32x4 v1 = *(const f32x4*)(localo + (size_t)gm * HID + col + 4);
            const f32x4 p0 = *(const f32x4*)(wpow + (size_t)tl * HID + col);
            const f32x4 p1 = *(const f32x4*)(wpow + (size_t)tl * HID + col + 4);
            const f32x4 c0 = *(const f32x4*)(crow + col);
            const f32x4 c1 = *(const f32x4*)(crow + col + 4);
            bf16x8 h8, l8;
#pragma unroll
            for (int e = 0; e < 4; ++e) {
                const float f0 = fmaf(p0[e], c0[e], v0[e]);
                const float f1 = fmaf(p1[e], c1[e], v1[e]);
                u16 a, b;
                splitf(f0, a, b); h8[e] = (short)a; l8[e] = (short)b;
                splitf(f1, a, b); h8[e + 4] = (short)a; l8[e + 4] = (short)b;
            }
            const int phys = r * 64 + ((gl ^ (r & 7)) * 8);
            *(bf16x8*)(Ah + phys) = h8;
            *(bf16x8*)(Al + phys) = l8;
        }
        __syncthreads();
#pragma unroll
        for (int ks = 0; ks < 2; ++ks) {
            const int colE = ks * 32 + kg * 8;
            bf16x8 ah[4], al[4], bh[4], bl[4];
#pragma unroll
            for (int f = 0; f < 4; ++f) {
                const int ra = wr * 64 + f * 16 + fr;
                const int pa = ra * 64 + (colE ^ ((fr & 7) << 3));
                ah[f] = *(const bf16x8*)(Ah + pa);
                al[f] = *(const bf16x8*)(Al + pa);
                const int rb = wc * 64 + f * 16 + fr;
                const int pb = rb * 64 + (colE ^ ((fr & 7) << 3));
                bh[f] = *(const bf16x8*)(Bh + pb);
                bl[f] = *(const bf16x8*)(Bl + pb);
            }
#pragma unroll
            for (int i = 0; i < 4; ++i)
#pragma unroll
                for (int j = 0; j < 4; ++j) {
                    acc[i][j] = __builtin_amdgcn_mfma_f32_16x16x32_bf16(ah[i], bh[j], acc[i][j], 0, 0, 0);
                    acc[i][j] = __builtin_amdgcn_mfma_f32_16x16x32_bf16(ah[i], bl[j], acc[i][j], 0, 0, 0);
                    acc[i][j] = __builtin_amdgcn_mfma_f32_16x16x32_bf16(al[i], bh[j], acc[i][j], 0, 0, 0);
                }
        }
        __syncthreads();
    }

#pragma unroll
    for (int i = 0; i < 4; ++i) {
        const size_t row0 = (size_t)mBase + wr * 64 + i * 16 + kg * 4;
#pragma unroll
        for (int j = 0; j < 4; ++j) {
            const int col = nBase + wc * 64 + j * 16 + fr;
#pragma unroll
            for (int rg = 0; rg < 4; ++rg)
                C[(row0 + rg) * DOUT + col] = acc[i][j][rg];
        }
    }
}

// ---------------------------------------------------------------------------
extern "C" void kernel_launch(void* const* d_in, const int* in_sizes, int n_in,
                              void* d_out, int out_size, void* d_ws, size_t ws_size,
                              hipStream_t stream) {
    const float* x     = (const float*)d_in[0];   // [16,4096,256]
    const float* W_in  = (const float*)d_in[1];   // [512,256]
    const float* W_h   = (const float*)d_in[2];   // [512,512] (diagonal)
    const float* W_out = (const float*)d_in[3];   // [256,512]
    float* out = (float*)d_out;                    // [16,4096,256]

    // workspace layout (137,627,648 B total)
    char* ws = (char*)d_ws;
    float* localo = (float*)(ws);                      // 134,217,728 (fp32 local state)
    float* L      = (float*)(ws + 134217728);          // 1,048,576
    float* carry  = (float*)(ws + 135266304);          // 1,048,576
    float* wpow   = (float*)(ws + 136314880);          // 262,144
    float* wdiag  = (float*)(ws + 136577024);          // 2,048
    u16*   Winhi  = (u16*)(ws + 136579072);            // 262,144
    u16*   Winlo  = (u16*)(ws + 136841216);            // 262,144
    u16*   Wouthi = (u16*)(ws + 137103360);            // 262,144
    u16*   Woutlo = (u16*)(ws + 137365504);            // 262,144

    prep<<<257, 256, 0, stream>>>(W_h, W_in, W_out, wdiag, wpow,
                                  Winhi, Winlo, Wouthi, Woutlo);
    gemm1_scan<<<2048, 256, 0, stream>>>(x, Winhi, Winlo, localo, L, wdiag, wpow);
    scan_carry<<<32, 256, 0, stream>>>(L, wpow, carry);
    gemm2_fix<<<1024, 256, 0, stream>>>(localo, Wouthi, Woutlo, wpow, carry, out);
}